// Round 1
// baseline (1515.297 us; speedup 1.0000x reference)
//
#include <hip/hip_runtime.h>
#include <hip/hip_bf16.h>
#include <math.h>

// Problem constants
#define B_   32
#define T_   128
#define TE_  128
#define U_   64
#define E_   512
#define V_   32000
#define G_   256   // 4*U

// ---------------------------------------------------------------------------
// K1: xz[row, g] = sum_e emb[dec[row], e] * Wx[e, g] + bias[g]
// one block per row (b*T+t), 256 threads (g)
// ---------------------------------------------------------------------------
__global__ void embed_xz_kernel(const int* __restrict__ dec,
                                const float* __restrict__ emb,
                                const float* __restrict__ Wx,
                                const float* __restrict__ bias,
                                float* __restrict__ xz) {
    int row = blockIdx.x;
    int g = threadIdx.x;
    __shared__ float x[E_];
    int tok = dec[row];
    const float4* er = (const float4*)(emb + (size_t)tok * E_);
    if (g < 128) ((float4*)x)[g] = er[g];
    __syncthreads();
    float acc = bias[g];
#pragma unroll 8
    for (int e = 0; e < E_; e++) acc += x[e] * Wx[e * G_ + g];
    xz[(size_t)row * G_ + g] = acc;
}

// ---------------------------------------------------------------------------
// K2: LSTM scan. one block per batch element, 256 threads (one per gate-unit).
// Wh column in registers, h/c in LDS. Writes seq into feat[:, 0:64].
// ---------------------------------------------------------------------------
__global__ void lstm_kernel(const float* __restrict__ xz,
                            const float* __restrict__ h0,
                            const float* __restrict__ c0,
                            const float* __restrict__ Wh,
                            float* __restrict__ feat,
                            float* __restrict__ hT,
                            float* __restrict__ cT) {
    int b = blockIdx.x;
    int g = threadIdx.x;   // 0..255
    float w[U_];
#pragma unroll
    for (int u = 0; u < U_; u++) w[u] = Wh[u * G_ + g];
    __shared__ float h[U_];
    __shared__ float c[U_];
    __shared__ float z[G_];
    if (g < U_) { h[g] = h0[b * U_ + g]; c[g] = c0[b * U_ + g]; }
    __syncthreads();
    const float* xzb = xz + (size_t)b * T_ * G_;
    for (int t = 0; t < T_; t++) {
        float acc = xzb[t * G_ + g];
#pragma unroll
        for (int u = 0; u < U_; u++) acc += h[u] * w[u];
        z[g] = acc;
        __syncthreads();
        if (g < U_) {
            float iv = 1.f / (1.f + expf(-z[g]));
            float fv = 1.f / (1.f + expf(-z[U_ + g]));
            float gv = tanhf(z[2 * U_ + g]);
            float ov = 1.f / (1.f + expf(-z[3 * U_ + g]));
            float cn = fv * c[g] + iv * gv;
            float hn = ov * tanhf(cn);
            c[g] = cn; h[g] = hn;
            feat[((size_t)b * T_ + t) * 2 * U_ + g] = hn;
        }
        __syncthreads();
    }
    if (g < U_) { hT[b * U_ + g] = h[g]; cT[b * U_ + g] = c[g]; }
}

// ---------------------------------------------------------------------------
// K3: Luong attention per (b,t). query = h_{t-1} (h0 at t=0).
// scores over 128 enc positions, softmax, ctx into feat[:, 64:128].
// one block per row, 128 threads.
// ---------------------------------------------------------------------------
__global__ void attn_kernel(const float* __restrict__ enc,
                            const float* __restrict__ h0,
                            float* __restrict__ feat) {
    int row = blockIdx.x;          // b*T + t
    int b = row >> 7;
    int t = row & (T_ - 1);
    int tid = threadIdx.x;         // 0..127
    __shared__ float kv[U_];
    __shared__ float at[TE_];
    __shared__ float red[TE_];
    if (tid < U_)
        kv[tid] = (t == 0) ? h0[b * U_ + tid] : feat[(size_t)(row - 1) * 2 * U_ + tid];
    __syncthreads();
    const float* encb = enc + (size_t)b * TE_ * U_;
    // score for enc position tid
    float s = 0.f;
    const float4* e4 = (const float4*)(encb + tid * U_);
#pragma unroll
    for (int u4 = 0; u4 < U_ / 4; u4++) {
        float4 ev = e4[u4];
        s += ev.x * kv[u4 * 4 + 0] + ev.y * kv[u4 * 4 + 1] +
             ev.z * kv[u4 * 4 + 2] + ev.w * kv[u4 * 4 + 3];
    }
    red[tid] = s;
    __syncthreads();
    for (int off = 64; off > 0; off >>= 1) {
        if (tid < off) red[tid] = fmaxf(red[tid], red[tid + off]);
        __syncthreads();
    }
    float m = red[0];
    __syncthreads();
    float e = expf(s - m);
    at[tid] = e;
    red[tid] = e;
    __syncthreads();
    for (int off = 64; off > 0; off >>= 1) {
        if (tid < off) red[tid] += red[tid + off];
        __syncthreads();
    }
    float inv_sum = 1.f / red[0];
    __syncthreads();
    // ctx[u] for u = tid < 64
    if (tid < U_) {
        float cacc = 0.f;
#pragma unroll 4
        for (int sx = 0; sx < TE_; sx++)
            cacc += at[sx] * encb[sx * U_ + tid];
        feat[(size_t)row * 2 * U_ + U_ + tid] = cacc * inv_sum;
    }
}

// ---------------------------------------------------------------------------
// K4a: logits = feat[4096,128] @ Wd[128,32000] + bd  -> d_out (as scratch)
// 64x64 tile per block, 256 threads, 4x4 accumulators per thread.
// ---------------------------------------------------------------------------
#define LDA_ 132
__global__ void gemm_logits_kernel(const float* __restrict__ feat,
                                   const float* __restrict__ Wd,
                                   const float* __restrict__ bd,
                                   float* __restrict__ out) {
    __shared__ float As[64 * LDA_];
    __shared__ float Bs[32 * 64];
    int tid = threadIdx.x;
    int colbase = blockIdx.x * 64;
    int rowbase = blockIdx.y * 64;
    int tx = tid & 15, ty = tid >> 4;

    // stage A tile (64 rows x 128 k) as float4
#pragma unroll
    for (int j = 0; j < 8; j++) {
        int fi = tid + j * 256;        // 0..2047 float4 index
        int r = fi >> 5, kq = fi & 31;
        float4 v = *(const float4*)(feat + (size_t)(rowbase + r) * 128 + kq * 4);
        *(float4*)(&As[r * LDA_ + kq * 4]) = v;
    }

    float acc[4][4] = {};
    for (int kc = 0; kc < 4; kc++) {
        __syncthreads();
#pragma unroll
        for (int j = 0; j < 8; j++) {
            int e = tid + j * 256;
            int k = e >> 6, cc = e & 63;
            Bs[k * 64 + cc] = Wd[(size_t)(kc * 32 + k) * V_ + colbase + cc];
        }
        __syncthreads();
#pragma unroll
        for (int kk = 0; kk < 32; kk++) {
            float a0 = As[(ty * 4 + 0) * LDA_ + kc * 32 + kk];
            float a1 = As[(ty * 4 + 1) * LDA_ + kc * 32 + kk];
            float a2 = As[(ty * 4 + 2) * LDA_ + kc * 32 + kk];
            float a3 = As[(ty * 4 + 3) * LDA_ + kc * 32 + kk];
            float4 bv = *(float4*)(&Bs[kk * 64 + tx * 4]);
            acc[0][0] += a0 * bv.x; acc[0][1] += a0 * bv.y; acc[0][2] += a0 * bv.z; acc[0][3] += a0 * bv.w;
            acc[1][0] += a1 * bv.x; acc[1][1] += a1 * bv.y; acc[1][2] += a1 * bv.z; acc[1][3] += a1 * bv.w;
            acc[2][0] += a2 * bv.x; acc[2][1] += a2 * bv.y; acc[2][2] += a2 * bv.z; acc[2][3] += a2 * bv.w;
            acc[3][0] += a3 * bv.x; acc[3][1] += a3 * bv.y; acc[3][2] += a3 * bv.z; acc[3][3] += a3 * bv.w;
        }
    }
    int gc = colbase + tx * 4;
    float b0 = bd[gc], b1 = bd[gc + 1], b2 = bd[gc + 2], b3 = bd[gc + 3];
#pragma unroll
    for (int i = 0; i < 4; i++) {
        int gr = rowbase + ty * 4 + i;
        float4 o;
        o.x = acc[i][0] + b0; o.y = acc[i][1] + b1;
        o.z = acc[i][2] + b2; o.w = acc[i][3] + b3;
        *(float4*)(out + (size_t)gr * V_ + gc) = o;
    }
}

// ---------------------------------------------------------------------------
// K4b: per-row online max + sumexp over 32000 logits
// ---------------------------------------------------------------------------
__global__ void rowstats_kernel(const float* __restrict__ out,
                                float* __restrict__ stats) {
    int row = blockIdx.x;
    int tid = threadIdx.x;
    const float* p = out + (size_t)row * V_;
    float m = -1e30f, s = 0.f;
    for (int v = tid; v < V_; v += 256) {
        float l = p[v];
        float mn = fmaxf(m, l);
        s = s * expf(m - mn) + expf(l - mn);
        m = mn;
    }
    __shared__ float ms[256], ss[256];
    ms[tid] = m; ss[tid] = s;
    __syncthreads();
    for (int off = 128; off > 0; off >>= 1) {
        if (tid < off) {
            float m2 = ms[tid + off], s2 = ss[tid + off];
            float mn = fmaxf(ms[tid], m2);
            ss[tid] = ss[tid] * expf(ms[tid] - mn) + s2 * expf(m2 - mn);
            ms[tid] = mn;
        }
        __syncthreads();
    }
    if (tid == 0) { stats[row * 2] = ms[0]; stats[row * 2 + 1] = ss[0]; }
}

// ---------------------------------------------------------------------------
// K4c: out = exp(logit - m) / s, in place. grid (32, 4096)
// ---------------------------------------------------------------------------
__global__ void norm_kernel(float* __restrict__ out,
                            const float* __restrict__ stats) {
    int row = blockIdx.y;
    int v = (blockIdx.x * 256 + threadIdx.x) * 4;
    if (v >= V_) return;
    float m = stats[row * 2];
    float inv = 1.f / stats[row * 2 + 1];
    float4* p = (float4*)(out + (size_t)row * V_ + v);
    float4 x = *p;
    x.x = expf(x.x - m) * inv;
    x.y = expf(x.y - m) * inv;
    x.z = expf(x.z - m) * inv;
    x.w = expf(x.w - m) * inv;
    *p = x;
}

extern "C" void kernel_launch(void* const* d_in, const int* in_sizes, int n_in,
                              void* d_out, int out_size, void* d_ws, size_t ws_size,
                              hipStream_t stream) {
    const float* enc  = (const float*)d_in[0];
    const int*   dec  = (const int*)d_in[1];
    const float* h0   = (const float*)d_in[2];
    const float* c0   = (const float*)d_in[3];
    const float* emb  = (const float*)d_in[4];
    const float* Wx   = (const float*)d_in[5];
    const float* Wh   = (const float*)d_in[6];
    const float* bias = (const float*)d_in[7];
    const float* Wd   = (const float*)d_in[8];
    const float* bd   = (const float*)d_in[9];
    float* out = (float*)d_out;
    float* ws  = (float*)d_ws;

    const int NROW = B_ * T_;                  // 4096
    float* xz    = ws;                         // 4096*256
    float* feat  = xz + (size_t)NROW * G_;     // 4096*128
    float* stats = feat + (size_t)NROW * 2 * U_; // 4096*2
    float* hT = out + (size_t)NROW * V_;       // 131072000
    float* cT = hT + B_ * U_;

    embed_xz_kernel<<<dim3(NROW), 256, 0, stream>>>(dec, emb, Wx, bias, xz);
    lstm_kernel<<<dim3(B_), 256, 0, stream>>>(xz, h0, c0, Wh, feat, hT, cT);
    attn_kernel<<<dim3(NROW), 128, 0, stream>>>(enc, h0, feat);
    gemm_logits_kernel<<<dim3(V_ / 64, NROW / 64), 256, 0, stream>>>(feat, Wd, bd, out);
    rowstats_kernel<<<dim3(NROW), 256, 0, stream>>>(out, stats);
    norm_kernel<<<dim3(32, NROW), 256, 0, stream>>>(out, stats);
}

// Round 2
// 1256.955 us; speedup vs baseline: 1.2055x; 1.2055x over previous
//
#include <hip/hip_runtime.h>
#include <hip/hip_bf16.h>
#include <math.h>

// Problem constants
#define B_   32
#define T_   128
#define TE_  128
#define U_   64
#define E_   512
#define V_   32000
#define G_   256   // 4*U

typedef __attribute__((ext_vector_type(8))) short  short8x;
typedef __attribute__((ext_vector_type(4))) float  f32x4;
typedef __attribute__((ext_vector_type(4))) unsigned short u16x4;

__device__ inline unsigned short f2bf(float x) {
    union { float f; unsigned int u; } v; v.f = x;
    unsigned int u = v.u;
    u = (u + 0x7FFFu + ((u >> 16) & 1u)) >> 16;   // round-to-nearest-even
    return (unsigned short)u;
}

// ---------------------------------------------------------------------------
// K1: xz[row, g] = sum_e emb[dec[row], e] * Wx[e, g] + bias[g]
// 16 rows per block, 256 threads (col g). emb rows staged in LDS;
// Wx read once per block (L2-resident across 256 blocks).
// ---------------------------------------------------------------------------
__global__ void embed_xz_kernel(const int* __restrict__ dec,
                                const float* __restrict__ emb,
                                const float* __restrict__ Wx,
                                const float* __restrict__ bias,
                                float* __restrict__ xz) {
    __shared__ float xs[16][E_];           // 32 KB
    int tid = threadIdx.x;
    int rb = blockIdx.x * 16;
    // stage 16 embedding rows: 16*512 = 8192 floats = 2048 float4
#pragma unroll
    for (int i = 0; i < 8; i++) {
        int idx = tid + i * 256;           // float4 index, 0..2047
        int r = idx >> 7, q = idx & 127;
        ((float4*)xs[r])[q] = ((const float4*)(emb + (size_t)dec[rb + r] * E_))[q];
    }
    __syncthreads();
    float acc[16];
#pragma unroll
    for (int r = 0; r < 16; r++) acc[r] = 0.f;
    for (int e = 0; e < E_; e++) {
        float w = Wx[e * G_ + tid];
#pragma unroll
        for (int r = 0; r < 16; r++) acc[r] += xs[r][e] * w;
    }
    float bv = bias[tid];
#pragma unroll
    for (int r = 0; r < 16; r++)
        xz[(size_t)(rb + r) * G_ + tid] = acc[r] + bv;
}

// ---------------------------------------------------------------------------
// K2: LSTM scan. one block per batch element, 256 threads (one per gate-unit).
// ---------------------------------------------------------------------------
__global__ void lstm_kernel(const float* __restrict__ xz,
                            const float* __restrict__ h0,
                            const float* __restrict__ c0,
                            const float* __restrict__ Wh,
                            float* __restrict__ feat,
                            float* __restrict__ hT,
                            float* __restrict__ cT) {
    int b = blockIdx.x;
    int g = threadIdx.x;   // 0..255
    float w[U_];
#pragma unroll
    for (int u = 0; u < U_; u++) w[u] = Wh[u * G_ + g];
    __shared__ float h[U_];
    __shared__ float c[U_];
    __shared__ float z[G_];
    if (g < U_) { h[g] = h0[b * U_ + g]; c[g] = c0[b * U_ + g]; }
    __syncthreads();
    const float* xzb = xz + (size_t)b * T_ * G_;
    for (int t = 0; t < T_; t++) {
        float acc = xzb[t * G_ + g];
#pragma unroll
        for (int u = 0; u < U_; u++) acc += h[u] * w[u];
        z[g] = acc;
        __syncthreads();
        if (g < U_) {
            float iv = 1.f / (1.f + expf(-z[g]));
            float fv = 1.f / (1.f + expf(-z[U_ + g]));
            float gv = tanhf(z[2 * U_ + g]);
            float ov = 1.f / (1.f + expf(-z[3 * U_ + g]));
            float cn = fv * c[g] + iv * gv;
            float hn = ov * tanhf(cn);
            c[g] = cn; h[g] = hn;
            feat[((size_t)b * T_ + t) * 2 * U_ + g] = hn;
        }
        __syncthreads();
    }
    if (g < U_) { hT[b * U_ + g] = h[g]; cT[b * U_ + g] = c[g]; }
}

// ---------------------------------------------------------------------------
// K3: Luong attention per (b,t). query = h_{t-1} (h0 at t=0).
// ---------------------------------------------------------------------------
__global__ void attn_kernel(const float* __restrict__ enc,
                            const float* __restrict__ h0,
                            float* __restrict__ feat) {
    int row = blockIdx.x;          // b*T + t
    int b = row >> 7;
    int t = row & (T_ - 1);
    int tid = threadIdx.x;         // 0..127
    __shared__ float kv[U_];
    __shared__ float at[TE_];
    __shared__ float red[TE_];
    if (tid < U_)
        kv[tid] = (t == 0) ? h0[b * U_ + tid] : feat[(size_t)(row - 1) * 2 * U_ + tid];
    __syncthreads();
    const float* encb = enc + (size_t)b * TE_ * U_;
    float s = 0.f;
    const float4* e4 = (const float4*)(encb + tid * U_);
#pragma unroll
    for (int u4 = 0; u4 < U_ / 4; u4++) {
        float4 ev = e4[u4];
        s += ev.x * kv[u4 * 4 + 0] + ev.y * kv[u4 * 4 + 1] +
             ev.z * kv[u4 * 4 + 2] + ev.w * kv[u4 * 4 + 3];
    }
    red[tid] = s;
    __syncthreads();
    for (int off = 64; off > 0; off >>= 1) {
        if (tid < off) red[tid] = fmaxf(red[tid], red[tid + off]);
        __syncthreads();
    }
    float m = red[0];
    __syncthreads();
    float e = expf(s - m);
    at[tid] = e;
    red[tid] = e;
    __syncthreads();
    for (int off = 64; off > 0; off >>= 1) {
        if (tid < off) red[tid] += red[tid + off];
        __syncthreads();
    }
    float inv_sum = 1.f / red[0];
    __syncthreads();
    if (tid < U_) {
        float cacc = 0.f;
#pragma unroll 4
        for (int sx = 0; sx < TE_; sx++)
            cacc += at[sx] * encb[sx * U_ + tid];
        feat[(size_t)row * 2 * U_ + U_ + tid] = cacc * inv_sum;
    }
}

// ---------------------------------------------------------------------------
// K3b: feat fp32 -> bf16
// ---------------------------------------------------------------------------
__global__ void feat_to_bf16(const float* __restrict__ feat,
                             unsigned short* __restrict__ fb) {
    int i = blockIdx.x * 256 + threadIdx.x;   // float4 index, 131072 total
    float4 v = ((const float4*)feat)[i];
    u16x4 o;
    o.x = f2bf(v.x); o.y = f2bf(v.y); o.z = f2bf(v.z); o.w = f2bf(v.w);
    *(u16x4*)(fb + (size_t)i * 4) = o;
}

// ---------------------------------------------------------------------------
// K3c: Wd [128][32000] fp32 -> Wd_t [32000][128] bf16 (transposed)
// block: 64 n-cols, grid 500
// ---------------------------------------------------------------------------
__global__ void wd_transpose(const float* __restrict__ Wd,
                             unsigned short* __restrict__ wdt) {
    __shared__ float t[128][65];               // 33.3 KB
    int tid = threadIdx.x;
    int nb = blockIdx.x * 64;
#pragma unroll
    for (int i = 0; i < 32; i++) {
        int idx = tid + i * 256;               // 0..8191
        int k = idx >> 6, n = idx & 63;
        t[k][n] = Wd[(size_t)k * V_ + nb + n];
    }
    __syncthreads();
    int n = tid >> 2, kq = tid & 3;            // 64 rows x 4 k-quarters(32 each)
#pragma unroll
    for (int g = 0; g < 4; g++) {
        short8x s;
#pragma unroll
        for (int j = 0; j < 8; j++)
            s[j] = (short)f2bf(t[kq * 32 + g * 8 + j][n]);
        *(short8x*)(wdt + (size_t)(nb + n) * 128 + kq * 32 + g * 8) = s;
    }
}

// ---------------------------------------------------------------------------
// K4a: GEMM pass 1 — per-row sum(exp(logit)) partials, nothing materialized.
// grid (64 row-blocks, 25 col-blocks of 1280). 256 thr = 4 waves,
// wave handles 16 rows x 128 cols per chunk, 10 chunks.
// MFMA 16x16x32 bf16; A & B fragments are direct 16B coalesced loads.
// ---------------------------------------------------------------------------
__global__ void gemm_stats(const unsigned short* __restrict__ fb,
                           const unsigned short* __restrict__ wdt,
                           const float* __restrict__ bd,
                           float* __restrict__ partial) {
    int tid = threadIdx.x;
    int lane = tid & 63, wave = tid >> 6;
    int lrow = lane & 15, quad = lane >> 4;
    int rowbase = blockIdx.x * 64 + wave * 16;
    int cb = blockIdx.y;
    int col0 = cb * 1280;

    short8x a[4];
    const unsigned short* ap = fb + (size_t)(rowbase + lrow) * 128 + quad * 8;
#pragma unroll
    for (int k = 0; k < 4; k++) a[k] = *(const short8x*)(ap + k * 32);

    float s[4] = {0.f, 0.f, 0.f, 0.f};
    for (int ch = 0; ch < 10; ch++) {
        int cc = col0 + ch * 128;
        f32x4 acc[8];
#pragma unroll
        for (int ct = 0; ct < 8; ct++) acc[ct] = {0.f, 0.f, 0.f, 0.f};
        const unsigned short* bp = wdt + (size_t)(cc + lrow) * 128 + quad * 8;
#pragma unroll
        for (int ct = 0; ct < 8; ct++) {
#pragma unroll
            for (int k = 0; k < 4; k++) {
                short8x b = *(const short8x*)(bp + (size_t)ct * 16 * 128 + k * 32);
                acc[ct] = __builtin_amdgcn_mfma_f32_16x16x32_bf16(a[k], b, acc[ct], 0, 0, 0);
            }
        }
#pragma unroll
        for (int ct = 0; ct < 8; ct++) {
            float bdv = bd[cc + ct * 16 + lrow];
#pragma unroll
            for (int r = 0; r < 4; r++)
                s[r] += __expf(acc[ct][r] + bdv);
        }
    }
    // reduce across the 16 lanes holding the same rows (lane-xor 1,2,4,8)
#pragma unroll
    for (int r = 0; r < 4; r++) {
        float v = s[r];
        v += __shfl_xor(v, 1);
        v += __shfl_xor(v, 2);
        v += __shfl_xor(v, 4);
        v += __shfl_xor(v, 8);
        if (lrow == 0)
            partial[(size_t)(rowbase + quad * 4 + r) * 25 + cb] = v;
    }
}

// ---------------------------------------------------------------------------
// K4b: merge partials -> inv_s[row]
// ---------------------------------------------------------------------------
__global__ void merge_stats(const float* __restrict__ partial,
                            float* __restrict__ inv_s) {
    int r = blockIdx.x * 256 + threadIdx.x;   // 4096
    float s = 0.f;
#pragma unroll
    for (int i = 0; i < 25; i++) s += partial[(size_t)r * 25 + i];
    inv_s[r] = 1.f / s;
}

// ---------------------------------------------------------------------------
// K4c: GEMM pass 2 — recompute logits, write exp(l)*inv_s via LDS transpose
// so global stores are 512B-contiguous float4 runs.
// ---------------------------------------------------------------------------
__global__ void gemm_norm(const unsigned short* __restrict__ fb,
                          const unsigned short* __restrict__ wdt,
                          const float* __restrict__ bd,
                          const float* __restrict__ inv_s,
                          float* __restrict__ out) {
    __shared__ float lds[64 * 132];            // 33.8 KB, pad 132 breaks conflicts
    int tid = threadIdx.x;
    int lane = tid & 63, wave = tid >> 6;
    int lrow = lane & 15, quad = lane >> 4;
    int rowblk = blockIdx.x * 64;
    int rowbase = rowblk + wave * 16;
    int col0 = blockIdx.y * 1280;

    short8x a[4];
    const unsigned short* ap = fb + (size_t)(rowbase + lrow) * 128 + quad * 8;
#pragma unroll
    for (int k = 0; k < 4; k++) a[k] = *(const short8x*)(ap + k * 32);

    float inv[4];
#pragma unroll
    for (int r = 0; r < 4; r++) inv[r] = inv_s[rowbase + quad * 4 + r];

    for (int ch = 0; ch < 10; ch++) {
        int cc = col0 + ch * 128;
        f32x4 acc[8];
#pragma unroll
        for (int ct = 0; ct < 8; ct++) acc[ct] = {0.f, 0.f, 0.f, 0.f};
        const unsigned short* bp = wdt + (size_t)(cc + lrow) * 128 + quad * 8;
#pragma unroll
        for (int ct = 0; ct < 8; ct++) {
#pragma unroll
            for (int k = 0; k < 4; k++) {
                short8x b = *(const short8x*)(bp + (size_t)ct * 16 * 128 + k * 32);
                acc[ct] = __builtin_amdgcn_mfma_f32_16x16x32_bf16(a[k], b, acc[ct], 0, 0, 0);
            }
        }
        __syncthreads();   // previous chunk's LDS reads complete
#pragma unroll
        for (int ct = 0; ct < 8; ct++) {
            float bdv = bd[cc + ct * 16 + lrow];
#pragma unroll
            for (int r = 0; r < 4; r++)
                lds[(wave * 16 + quad * 4 + r) * 132 + ct * 16 + lrow] =
                    __expf(acc[ct][r] + bdv) * inv[r];
        }
        __syncthreads();
        // cooperative coalesced store: 64 rows x 128 cols = 2048 float4
#pragma unroll
        for (int i = 0; i < 8; i++) {
            int idx = tid + i * 256;
            int r = idx >> 5, c4 = idx & 31;
            float4 v = *(float4*)&lds[r * 132 + c4 * 4];
            *(float4*)(out + (size_t)(rowblk + r) * V_ + cc + c4 * 4) = v;
        }
    }
}

extern "C" void kernel_launch(void* const* d_in, const int* in_sizes, int n_in,
                              void* d_out, int out_size, void* d_ws, size_t ws_size,
                              hipStream_t stream) {
    const float* enc  = (const float*)d_in[0];
    const int*   dec  = (const int*)d_in[1];
    const float* h0   = (const float*)d_in[2];
    const float* c0   = (const float*)d_in[3];
    const float* emb  = (const float*)d_in[4];
    const float* Wx   = (const float*)d_in[5];
    const float* Wh   = (const float*)d_in[6];
    const float* bias = (const float*)d_in[7];
    const float* Wd   = (const float*)d_in[8];
    const float* bd   = (const float*)d_in[9];
    float* out = (float*)d_out;
    float* ws  = (float*)d_ws;

    const int NROW = B_ * T_;                       // 4096
    float* xz      = ws;                            // 1,048,576 f
    float* feat    = xz + (size_t)NROW * G_;        //   524,288 f
    float* partial = feat + (size_t)NROW * 2 * U_;  //   102,400 f
    float* inv_s   = partial + (size_t)NROW * 25;   //     4,096 f
    unsigned short* fb  = (unsigned short*)(inv_s + NROW);          // 524,288 u16
    unsigned short* wdt = (unsigned short*)(fb + (size_t)NROW * 2 * U_); // 4,096,000 u16
    float* hT = out + (size_t)NROW * V_;
    float* cT = hT + B_ * U_;

    wd_transpose<<<dim3(V_ / 64), 256, 0, stream>>>(Wd, wdt);
    embed_xz_kernel<<<dim3(NROW / 16), 256, 0, stream>>>(dec, emb, Wx, bias, xz);
    lstm_kernel<<<dim3(B_), 256, 0, stream>>>(xz, h0, c0, Wh, feat, hT, cT);
    attn_kernel<<<dim3(NROW), 128, 0, stream>>>(enc, h0, feat);
    feat_to_bf16<<<dim3(NROW * 2 * U_ / 1024), 256, 0, stream>>>(feat, fb);
    gemm_stats<<<dim3(64, 25), 256, 0, stream>>>(fb, wdt, bd, partial);
    merge_stats<<<dim3(NROW / 256), 256, 0, stream>>>(partial, inv_s);
    gemm_norm<<<dim3(64, 25), 256, 0, stream>>>(fb, wdt, bd, inv_s, out);
}